// Round 16
// baseline (179.006 us; speedup 1.0000x reference)
//
#include <hip/hip_runtime.h>

// OneDilate: out[b,c,i,j] = 50 - 0.5 * sum_{10x10 clamped window} x
// r15 skeleton (one-shot blocks, global_load_lds staging, 34KB LDS,
// 4 blocks/CU, 6144 blocks) + SEPARABLE phase B (V10 then H10).
//  r15 result: residency lever worked (occ 52%, VALU 55% -- first hot pipe
//  in 15 rounds) but fused B recomputes H-sums 5.5x/output -> VALU ~34us
//  co-limits. Separable shares each vertical sum across 128 column-threads:
//  per-thread VALU ~550 -> ~170, ds ops 44 -> 21.
//  B1: 11 column float4 reads from T (lane-consecutive) -> tree+slide ->
//      2 V rows in regs; barrier; write V over T rows 0..7 (dead); barrier.
//  B2: proven H-sum code on V rows, 2 output rows/thread, float4 stores.

#define IMG 512
#define OUTW 511
#define KS 10
#define MEAN 4
#define SUBB 8                   // output rows per block
#define TS (SUBB + KS - 1)       // 17 staged rows
#define ROWF4 (IMG / 4)          // 128 float4 per row
#define NF4 (TS * ROWF4)         // 2176 float4 = 34 KiB LDS
#define NTHREADS 512
#define NBANDS (IMG / SUBB)      // 64
#define NIMG 96                  // 32 * 3 images
#define NWG (NBANDS * NIMG)      // 6144 (divisible by 8 XCDs)
#define CPX (NWG / 8)            // 768 per XCD chunk

__device__ __forceinline__ float4 f4add(float4 a, float4 b) {
    return make_float4(a.x + b.x, a.y + b.y, a.z + b.z, a.w + b.w);
}

__global__ __launch_bounds__(NTHREADS) void onedilate_kernel(
    const float* __restrict__ x, float* __restrict__ out)
{
    __shared__ float smemf[TS * IMG];   // 34816 B -> 4 blocks/CU

    // Bijective XCD-aware swizzle: each XCD owns a contiguous chunk of
    // (band, image); adjacent bands of one image share halo rows in L2.
    const int lin = blockIdx.y * NBANDS + blockIdx.x;
    const int swz = (lin & 7) * CPX + (lin >> 3);
    const int bx  = swz & (NBANDS - 1);  // band
    const int bc  = swz >> 6;            // image (NBANDS == 64)

    const int tid = threadIdx.x;
    const int rb  = bx * SUBB;           // first output row of this band

    const float* __restrict__ xim = x + (size_t)bc * (IMG * IMG);
    float* __restrict__ oim = out + (size_t)bc * (OUTW * OUTW);

    // ---------------- Phase A: async stage tile into LDS ----------------
    // idx -> (row r = idx>>7, colgroup c4 = idx&127); row clamped at stage.
    // LDS byte offset = idx*16: linear in tid (HW wave-base + lane*16, m104).
#define STAGE1(idx_)                                                       \
    {                                                                      \
        const int r_  = (idx_) >> 7;                                       \
        const int c4_ = (idx_) & (ROWF4 - 1);                              \
        const int ri_ = min(max(rb - MEAN + r_, 0), IMG - 1);              \
        __builtin_amdgcn_global_load_lds(                                  \
            (const __attribute__((address_space(1))) void*)                \
                (xim + (size_t)ri_ * IMG + c4_ * 4),                       \
            (__attribute__((address_space(3))) void*)(smemf + (idx_) * 4), \
            16, 0, 0);                                                     \
    }
#pragma unroll
    for (int k = 0; k < 4; ++k) STAGE1(k * NTHREADS + tid)
    if (tid < (NF4 - 4 * NTHREADS)) STAGE1(4 * NTHREADS + tid)  // waves 0-1 full
#undef STAGE1
    __syncthreads();   // drains the global_load_lds queue

    const int jc = tid & 127;            // float4 col group 0..127
    const int rg = tid >> 7;             // row group 0..3 (2 rows each)

    // ---------------- B1: vertical 10-sums (column-local) ----------------
    // Thread's output rows i0,i0+1 need T rows 2rg..2rg+10 (pre-clamped).
    float4 v0, v1;
    {
        const float4* Tv = (const float4*)smemf;
        float4 t[11];
#pragma unroll
        for (int k = 0; k < 11; ++k)
            t[k] = Tv[(size_t)(2 * rg + k) * ROWF4 + jc];
        const float4 s01 = f4add(t[0], t[1]), s23 = f4add(t[2], t[3]);
        const float4 s45 = f4add(t[4], t[5]), s67 = f4add(t[6], t[7]);
        const float4 s89 = f4add(t[8], t[9]);
        v0 = f4add(f4add(f4add(s01, s23), f4add(s45, s67)), s89);
        v1 = make_float4(v0.x + t[10].x - t[0].x, v0.y + t[10].y - t[0].y,
                         v0.z + t[10].z - t[0].z, v0.w + t[10].w - t[0].w);
    }
    __syncthreads();   // all B1 reads of T complete -> rows 0..7 are dead
    {
        float4* Vv = (float4*)smemf;
        Vv[(size_t)(2 * rg + 0) * ROWF4 + jc] = v0;
        Vv[(size_t)(2 * rg + 1) * ROWF4 + jc] = v1;
    }
    __syncthreads();   // V rows 0..7 visible across waves (B2 reads columns
                       // written by other waves of the same rg pair)

    // ---------------- B2: horizontal 10-sums V -> out ----------------
    const int cbase = 4 * jc;
    const int bl0 = max(cbase - 4, 0);        // only jc=0 OOB-low
    const int bl2 = min(cbase + 4, IMG - 4);  // only jc=127 OOB-high
    const int bl3 = min(cbase + 8, IMG - 4);  // jc=126,127 OOB-high
    const bool lo0 = (cbase - 4 < 0);
    const bool hi2 = (cbase + 4 > IMG - 4);
    const bool hi3 = (cbase + 8 > IMG - 4);

    const int i0 = rb + 2 * rg;
#pragma unroll
    for (int k = 0; k < 2; ++k) {
        const float* rp = smemf + (size_t)(2 * rg + k) * IMG;
        float4 w0 = *(const float4*)(rp + bl0);
        float4 w1 = *(const float4*)(rp + cbase);
        float4 w2 = *(const float4*)(rp + bl2);
        float4 w3 = *(const float4*)(rp + bl3);
        if (lo0) w0 = make_float4(w0.x, w0.x, w0.x, w0.x);  // col 0 replicate
        if (hi2) w2 = make_float4(w2.w, w2.w, w2.w, w2.w);  // col 511 replicate
        const float w12 = hi3 ? w3.w : w3.x;                // col min(4jc+8,511)

        const float S = ((w0.x + w0.y) + (w0.z + w0.w))
                      + ((w1.x + w1.y) + (w1.z + w1.w))
                      + (w2.x + w2.y);
        const float d1  = w2.z - w0.x;
        const float d2  = w2.w - w0.y;
        const float d3  = w12  - w0.z;
        const float d12 = d1 + d2;

        const int i = i0 + k;
        if (i < OUTW) {                   // only band 63 / rg 3 / k=1 fails
            float* op = oim + (size_t)i * OUTW + cbase;
            const float4 o = make_float4(fmaf(S, -0.5f, 50.0f),
                                         fmaf(S + d1, -0.5f, 50.0f),
                                         fmaf(S + d12, -0.5f, 50.0f),
                                         fmaf(S + (d12 + d3), -0.5f, 50.0f));
            if (cbase + 3 < OUTW) {
                *(float4*)op = o;         // dwordx4, 4B-aligned (proven)
            } else {                      // jc=127: cols 508..510 only
                op[0] = o.x; op[1] = o.y; op[2] = o.z;
            }
        }
    }
}

extern "C" void kernel_launch(void* const* d_in, const int* in_sizes, int n_in,
                              void* d_out, int out_size, void* d_ws, size_t ws_size,
                              hipStream_t stream) {
    const float* x = (const float*)d_in[0];
    float* out = (float*)d_out;

    dim3 block(NTHREADS, 1, 1);
    dim3 grid(NBANDS, NIMG, 1);   // 64 x 96 = 6144 blocks
    onedilate_kernel<<<grid, block, 0, stream>>>(x, out);
}